// Round 1
// baseline (376.754 us; speedup 1.0000x reference)
//
#include <hip/hip_runtime.h>

#define HH 256
#define WW 256
#define NB 4
#define NC 128

// ---------------- downsample kernels ----------------
// 2x downsample (256->128): avg of rows {2y,2y+1} x cols {2x,2x+1}
__global__ void ds2x_kernel(const float* __restrict__ in, float* __restrict__ out, int total) {
    int idx = blockIdx.x * blockDim.x + threadIdx.x;
    if (idx >= total) return;
    int x = idx & 127;
    int t = idx >> 7;
    int y = t & 127;
    int bc = t >> 7;
    const float* p = in + (size_t)bc * (HH * WW) + (2 * y) * WW + 2 * x;
    float2 a = *(const float2*)p;
    float2 b = *(const float2*)(p + WW);
    out[idx] = 0.25f * (a.x + a.y + b.x + b.y);
}

// 4x downsample (256->64): avg of rows {4y+1,4y+2} x cols {4x+1,4x+2}
__global__ void ds4x_kernel(const float* __restrict__ in, float* __restrict__ out, int total) {
    int idx = blockIdx.x * blockDim.x + threadIdx.x;
    if (idx >= total) return;
    int x = idx & 63;
    int t = idx >> 6;
    int y = t & 63;
    int bc = t >> 6;
    const float* p = in + (size_t)bc * (HH * WW) + (4 * y + 1) * WW + 4 * x;
    float4 a = *(const float4*)p;
    float4 b = *(const float4*)(p + WW);
    out[idx] = 0.25f * (a.y + a.z + b.y + b.z);
}

// ---------------- deformable correlation ----------------
// One thread per output pixel at scale resolution; loop over 128 channels.
// Block = 256 threads = 32x8 pixel tile (coalesced f1, L1-local f2 gathers).
template <int SCALE>
__global__ void corr_kernel(const float* __restrict__ f1, const float* __restrict__ f2,
                            const float* __restrict__ offs, float* __restrict__ out) {
    constexpr int S = (SCALE == 0) ? 256 : (SCALE == 1 ? 128 : 64);
    int x = blockIdx.x * 32 + (threadIdx.x & 31);
    int y = blockIdx.y * 8 + (threadIdx.x >> 5);
    int b = blockIdx.z;

    const float* offx = offs + ((size_t)b * 6 + 2 * SCALE) * (HH * WW);
    const float* offy = offx + HH * WW;
    float dx, dy;
    if constexpr (SCALE == 0) {
        dx = offx[y * WW + x];
        dy = offy[y * WW + x];
    } else if constexpr (SCALE == 1) {
        const float* px = offx + (2 * y) * WW + 2 * x;
        const float* py = offy + (2 * y) * WW + 2 * x;
        dx = 0.125f * (px[0] + px[1] + px[WW] + px[WW + 1]);   // (2x2 avg) / 2
        dy = 0.125f * (py[0] + py[1] + py[WW] + py[WW + 1]);
    } else {
        const float* px = offx + (4 * y + 1) * WW + 4 * x + 1;
        const float* py = offy + (4 * y + 1) * WW + 4 * x + 1;
        dx = 0.0625f * (px[0] + px[1] + px[WW] + px[WW + 1]);  // (2x2 avg) / 4
        dy = 0.0625f * (py[0] + py[1] + py[WW] + py[WW + 1]);
    }

    float sx = (float)x + dx;
    float sy = (float)y + dy;
    float x0f = floorf(sx), y0f = floorf(sy);
    float wx1 = sx - x0f, wy1 = sy - y0f;
    float wx0 = 1.0f - wx1, wy0 = 1.0f - wy1;
    int x0 = (int)x0f, y0 = (int)y0f;
    int x1 = x0 + 1, y1 = y0 + 1;
    bool vx0 = (x0 >= 0) & (x0 < S);
    bool vx1 = (x1 >= 0) & (x1 < S);
    bool vy0 = (y0 >= 0) & (y0 < S);
    bool vy1 = (y1 >= 0) & (y1 < S);
    float w00 = wy0 * wx0 * (float)(vy0 & vx0);
    float w01 = wy0 * wx1 * (float)(vy0 & vx1);
    float w10 = wy1 * wx0 * (float)(vy1 & vx0);
    float w11 = wy1 * wx1 * (float)(vy1 & vx1);
    int cx0 = min(max(x0, 0), S - 1), cx1 = min(max(x1, 0), S - 1);
    int cy0 = min(max(y0, 0), S - 1), cy1 = min(max(y1, 0), S - 1);
    int i00 = cy0 * S + cx0, i01 = cy0 * S + cx1;
    int i10 = cy1 * S + cx0, i11 = cy1 * S + cx1;

    const float* f1p = f1 + ((size_t)b * NC) * (S * S) + y * S + x;
    const float* f2p = f2 + ((size_t)b * NC) * (S * S);
    float acc = 0.0f;
#pragma unroll 4
    for (int c = 0; c < NC; ++c) {
        float sv = w00 * f2p[i00] + w01 * f2p[i01] + w10 * f2p[i10] + w11 * f2p[i11];
        acc = fmaf(f1p[0], sv, acc);
        f1p += S * S;
        f2p += S * S;
    }

    if constexpr (SCALE == 0) {
        // write directly into output slice (b, 0, y, x) of (B,3,H,W)
        out[((size_t)b * 3) * (HH * WW) + y * WW + x] = acc;
    } else {
        out[(size_t)b * (S * S) + y * S + x] = acc;
    }
}

// ---------------- upsample corr back to 256x256 ----------------
template <int SCALE>
__global__ void up_kernel(const float* __restrict__ corr, float* __restrict__ out) {
    constexpr int S = (SCALE == 1) ? 128 : 64;
    constexpr float R = (float)S / 256.0f;
    int idx = blockIdx.x * blockDim.x + threadIdx.x;
    if (idx >= NB * HH * WW) return;
    int x = idx & 255;
    int t = idx >> 8;
    int y = t & 255;
    int b = t >> 8;
    float srcx = fminf(fmaxf(((float)x + 0.5f) * R - 0.5f, 0.0f), (float)(S - 1));
    float srcy = fminf(fmaxf(((float)y + 0.5f) * R - 0.5f, 0.0f), (float)(S - 1));
    int x0 = (int)srcx;
    int y0 = (int)srcy;
    int x1 = min(x0 + 1, S - 1), y1 = min(y0 + 1, S - 1);
    float wx = srcx - (float)x0, wy = srcy - (float)y0;
    const float* cp = corr + (size_t)b * (S * S);
    float v0 = cp[y0 * S + x0] * (1.0f - wx) + cp[y0 * S + x1] * wx;
    float v1 = cp[y1 * S + x0] * (1.0f - wx) + cp[y1 * S + x1] * wx;
    out[((size_t)b * 3 + SCALE) * (HH * WW) + y * WW + x] = (1.0f - wy) * v0 + wy * v1;
}

extern "C" void kernel_launch(void* const* d_in, const int* in_sizes, int n_in,
                              void* d_out, int out_size, void* d_ws, size_t ws_size,
                              hipStream_t stream) {
    const float* feat1 = (const float*)d_in[0];
    const float* feat2 = (const float*)d_in[1];
    const float* offs  = (const float*)d_in[2];
    float* out = (float*)d_out;
    float* ws = (float*)d_ws;

    const size_t n_ds1 = (size_t)NB * NC * 128 * 128;  // 8,388,608
    const size_t n_ds2 = (size_t)NB * NC * 64 * 64;    // 2,097,152
    const size_t n_c1  = (size_t)NB * 128 * 128;
    const size_t n_c2  = (size_t)NB * 64 * 64;
    const size_t need_bytes = (2 * n_ds1 + 2 * n_ds2 + n_c1 + n_c2) * sizeof(float);
    if (ws_size < need_bytes) return;  // workspace insufficient: bail cleanly

    float* ds1_f1 = ws;
    float* ds1_f2 = ds1_f1 + n_ds1;
    float* ds2_f1 = ds1_f2 + n_ds1;
    float* ds2_f2 = ds2_f1 + n_ds2;
    float* corr1  = ds2_f2 + n_ds2;
    float* corr2  = corr1 + n_c1;

    ds2x_kernel<<<(int)((n_ds1 + 255) / 256), 256, 0, stream>>>(feat1, ds1_f1, (int)n_ds1);
    ds2x_kernel<<<(int)((n_ds1 + 255) / 256), 256, 0, stream>>>(feat2, ds1_f2, (int)n_ds1);
    ds4x_kernel<<<(int)((n_ds2 + 255) / 256), 256, 0, stream>>>(feat1, ds2_f1, (int)n_ds2);
    ds4x_kernel<<<(int)((n_ds2 + 255) / 256), 256, 0, stream>>>(feat2, ds2_f2, (int)n_ds2);

    corr_kernel<0><<<dim3(8, 32, NB), 256, 0, stream>>>(feat1, feat2, offs, out);
    corr_kernel<1><<<dim3(4, 16, NB), 256, 0, stream>>>(ds1_f1, ds1_f2, offs, corr1);
    corr_kernel<2><<<dim3(2, 8, NB), 256, 0, stream>>>(ds2_f1, ds2_f2, offs, corr2);

    up_kernel<1><<<(NB * HH * WW + 255) / 256, 256, 0, stream>>>(corr1, out);
    up_kernel<2><<<(NB * HH * WW + 255) / 256, 256, 0, stream>>>(corr2, out);
}

// Round 2
// 217.842 us; speedup vs baseline: 1.7295x; 1.7295x over previous
//
#include <hip/hip_runtime.h>

#define HH 256
#define WW 256
#define NB 4
#define NC 128

// ---------- bf16 helpers (manual, RNE) ----------
__device__ __forceinline__ float blo(unsigned int u) {
    return __uint_as_float(u << 16);
}
__device__ __forceinline__ float bhi(unsigned int u) {
    return __uint_as_float(u & 0xffff0000u);
}
__device__ __forceinline__ unsigned int bf16_rne(float f) {
    unsigned int u = __float_as_uint(f);
    return (u + 0x7fffu + ((u >> 16) & 1u)) >> 16;  // finite inputs only
}
__device__ __forceinline__ unsigned int pack_bf16(float a, float b) {
    return bf16_rne(a) | (bf16_rne(b) << 16);
}

union U4 { uint4 v; unsigned int w[4]; };

// =====================================================================
// NEW PATH: CHW f32 -> HWC bf16 prep (transpose + downsample fused)
// Tile: 128 ch x 4 rows x 16 cols per block. LDS pitch 129 kills conflicts.
// =====================================================================
__global__ void prep_kernel(const float* __restrict__ src,
                            unsigned int* __restrict__ s0,   // (B,256,256,128) bf16 as uint pairs
                            unsigned int* __restrict__ d1,   // (B,128,128,128)
                            unsigned int* __restrict__ d2) { // (B, 64, 64,128)
    __shared__ float lds[64 * 129];
    int tid = threadIdx.x;
    int bx = blockIdx.x;   // 16 col tiles
    int by = blockIdx.y;   // 64 row tiles
    int b  = blockIdx.z;
    int x0 = bx * 16, y0 = by * 4;

    const float* sp = src + (size_t)b * NC * HH * WW;
#pragma unroll
    for (int k = 0; k < 32; ++k) {
        int idx = k * 256 + tid;
        int c  = idx >> 6;
        int pp = idx & 63;
        int py = pp >> 4, px = pp & 15;
        lds[pp * 129 + c] = sp[((size_t)c * HH + (y0 + py)) * WW + (x0 + px)];
    }
    __syncthreads();

    // scale 0 HWC (bf16 pairs): 4096 uints
#pragma unroll
    for (int k = 0; k < 16; ++k) {
        int idx = k * 256 + tid;
        int p = idx >> 6, cp = idx & 63;
        float a  = lds[p * 129 + 2 * cp];
        float bb = lds[p * 129 + 2 * cp + 1];
        int py = p >> 4, px = p & 15;
        size_t pix = ((size_t)b * HH + (y0 + py)) * WW + (x0 + px);
        s0[pix * 64 + cp] = pack_bf16(a, bb);
    }
    // scale 1 (2x2 avg of rows {2q,2q+1}): 16 pixels -> 1024 uints
#pragma unroll
    for (int k = 0; k < 4; ++k) {
        int idx = k * 256 + tid;
        int q = idx >> 6, cp = idx & 63;
        int qy = q >> 3, qx = q & 7;
        int p00 = (2 * qy) * 16 + 2 * qx;
        float a  = 0.25f * (lds[p00 * 129 + 2 * cp]     + lds[(p00 + 1) * 129 + 2 * cp] +
                            lds[(p00 + 16) * 129 + 2 * cp] + lds[(p00 + 17) * 129 + 2 * cp]);
        float bb = 0.25f * (lds[p00 * 129 + 2 * cp + 1]     + lds[(p00 + 1) * 129 + 2 * cp + 1] +
                            lds[(p00 + 16) * 129 + 2 * cp + 1] + lds[(p00 + 17) * 129 + 2 * cp + 1]);
        size_t pix = ((size_t)b * 128 + (2 * by + qy)) * 128 + (8 * bx + qx);
        d1[pix * 64 + cp] = pack_bf16(a, bb);
    }
    // scale 2 (avg rows {4y+1,4y+2} x cols {4x+1,4x+2}): 4 pixels -> 256 uints
    {
        int q = tid >> 6, cp = tid & 63;
        int p00 = 16 + 4 * q + 1;
        float a  = 0.25f * (lds[p00 * 129 + 2 * cp]     + lds[(p00 + 1) * 129 + 2 * cp] +
                            lds[(p00 + 16) * 129 + 2 * cp] + lds[(p00 + 17) * 129 + 2 * cp]);
        float bb = 0.25f * (lds[p00 * 129 + 2 * cp + 1]     + lds[(p00 + 1) * 129 + 2 * cp + 1] +
                            lds[(p00 + 16) * 129 + 2 * cp + 1] + lds[(p00 + 17) * 129 + 2 * cp + 1]);
        size_t pix = ((size_t)b * 64 + by) * 64 + (4 * bx + q);
        d2[pix * 64 + cp] = pack_bf16(a, bb);
    }
}

// =====================================================================
// HWC corr: 16 lanes per pixel, one uint4 (8 bf16 ch) per lane per vector.
// All 5 reads (f1 + 4 corners) are contiguous 256B per pixel.
// =====================================================================
template <int SCALE>
__global__ void corr_hwc(const unsigned int* __restrict__ f1,
                         const unsigned int* __restrict__ f2,
                         const float* __restrict__ offs,
                         float* __restrict__ out) {
    constexpr int S = (SCALE == 0) ? 256 : (SCALE == 1 ? 128 : 64);
    constexpr int LOGS = (SCALE == 0) ? 8 : (SCALE == 1 ? 7 : 6);
    int tid = threadIdx.x;
    int lane = tid & 15;
    int pix = blockIdx.x * 16 + (tid >> 4);
    int b = pix >> (2 * LOGS);
    int p = pix & (S * S - 1);
    int y = p >> LOGS;
    int x = p & (S - 1);

    const float* offx = offs + ((size_t)b * 6 + 2 * SCALE) * (HH * WW);
    const float* offy = offx + HH * WW;
    float dx, dy;
    if constexpr (SCALE == 0) {
        dx = offx[y * WW + x];
        dy = offy[y * WW + x];
    } else if constexpr (SCALE == 1) {
        const float* px = offx + (2 * y) * WW + 2 * x;
        const float* py = offy + (2 * y) * WW + 2 * x;
        dx = 0.125f * (px[0] + px[1] + px[WW] + px[WW + 1]);
        dy = 0.125f * (py[0] + py[1] + py[WW] + py[WW + 1]);
    } else {
        const float* px = offx + (4 * y + 1) * WW + 4 * x + 1;
        const float* py = offy + (4 * y + 1) * WW + 4 * x + 1;
        dx = 0.0625f * (px[0] + px[1] + px[WW] + px[WW + 1]);
        dy = 0.0625f * (py[0] + py[1] + py[WW] + py[WW + 1]);
    }

    float sx = (float)x + dx;
    float sy = (float)y + dy;
    float x0f = floorf(sx), y0f = floorf(sy);
    float wx1 = sx - x0f, wy1 = sy - y0f;
    float wx0 = 1.0f - wx1, wy0 = 1.0f - wy1;
    int x0 = (int)x0f, y0 = (int)y0f;
    int x1 = x0 + 1, y1 = y0 + 1;
    bool vx0 = (x0 >= 0) & (x0 < S);
    bool vx1 = (x1 >= 0) & (x1 < S);
    bool vy0 = (y0 >= 0) & (y0 < S);
    bool vy1 = (y1 >= 0) & (y1 < S);
    float w00 = wy0 * wx0 * (float)(vy0 & vx0);
    float w01 = wy0 * wx1 * (float)(vy0 & vx1);
    float w10 = wy1 * wx0 * (float)(vy1 & vx0);
    float w11 = wy1 * wx1 * (float)(vy1 & vx1);
    int cx0 = min(max(x0, 0), S - 1), cx1 = min(max(x1, 0), S - 1);
    int cy0 = min(max(y0, 0), S - 1), cy1 = min(max(y1, 0), S - 1);
    size_t pb = (size_t)b << (2 * LOGS);
    size_t i00 = pb + (cy0 << LOGS) + cx0, i01 = pb + (cy0 << LOGS) + cx1;
    size_t i10 = pb + (cy1 << LOGS) + cx0, i11 = pb + (cy1 << LOGS) + cx1;

    int lo = lane * 4;  // uint offset within the 64-uint channel vector
    U4 a, c00, c01, c10, c11;
    a.v   = *(const uint4*)(f1 + ((size_t)pix << 6) + lo);
    c00.v = *(const uint4*)(f2 + (i00 << 6) + lo);
    c01.v = *(const uint4*)(f2 + (i01 << 6) + lo);
    c10.v = *(const uint4*)(f2 + (i10 << 6) + lo);
    c11.v = *(const uint4*)(f2 + (i11 << 6) + lo);

    float acc = 0.0f;
#pragma unroll
    for (int j = 0; j < 4; ++j) {
        float s_lo = w00 * blo(c00.w[j]) + w01 * blo(c01.w[j]) + w10 * blo(c10.w[j]) + w11 * blo(c11.w[j]);
        float s_hi = w00 * bhi(c00.w[j]) + w01 * bhi(c01.w[j]) + w10 * bhi(c10.w[j]) + w11 * bhi(c11.w[j]);
        acc = fmaf(blo(a.w[j]), s_lo, acc);
        acc = fmaf(bhi(a.w[j]), s_hi, acc);
    }
    acc += __shfl_xor(acc, 8);
    acc += __shfl_xor(acc, 4);
    acc += __shfl_xor(acc, 2);
    acc += __shfl_xor(acc, 1);

    if (lane == 0) {
        if constexpr (SCALE == 0) {
            out[((size_t)b * 3) * (HH * WW) + p] = acc;
        } else {
            out[(size_t)b * (S * S) + p] = acc;
        }
    }
}

// ---------------- upsample corr back to 256x256 ----------------
template <int SCALE>
__global__ void up_kernel(const float* __restrict__ corr, float* __restrict__ out) {
    constexpr int S = (SCALE == 1) ? 128 : 64;
    constexpr float R = (float)S / 256.0f;
    int idx = blockIdx.x * blockDim.x + threadIdx.x;
    if (idx >= NB * HH * WW) return;
    int x = idx & 255;
    int t = idx >> 8;
    int y = t & 255;
    int b = t >> 8;
    float srcx = fminf(fmaxf(((float)x + 0.5f) * R - 0.5f, 0.0f), (float)(S - 1));
    float srcy = fminf(fmaxf(((float)y + 0.5f) * R - 0.5f, 0.0f), (float)(S - 1));
    int x0 = (int)srcx;
    int y0 = (int)srcy;
    int x1 = min(x0 + 1, S - 1), y1 = min(y0 + 1, S - 1);
    float wx = srcx - (float)x0, wy = srcy - (float)y0;
    const float* cp = corr + (size_t)b * (S * S);
    float v0 = cp[y0 * S + x0] * (1.0f - wx) + cp[y0 * S + x1] * wx;
    float v1 = cp[y1 * S + x0] * (1.0f - wx) + cp[y1 * S + x1] * wx;
    out[((size_t)b * 3 + SCALE) * (HH * WW) + y * WW + x] = (1.0f - wy) * v0 + wy * v1;
}

// =====================================================================
// FALLBACK PATH (round-1 kernels, CHW f32) — used only if ws too small
// =====================================================================
__global__ void ds2x_kernel(const float* __restrict__ in, float* __restrict__ out, int total) {
    int idx = blockIdx.x * blockDim.x + threadIdx.x;
    if (idx >= total) return;
    int x = idx & 127;
    int t = idx >> 7;
    int y = t & 127;
    int bc = t >> 7;
    const float* p = in + (size_t)bc * (HH * WW) + (2 * y) * WW + 2 * x;
    float2 a = *(const float2*)p;
    float2 b = *(const float2*)(p + WW);
    out[idx] = 0.25f * (a.x + a.y + b.x + b.y);
}
__global__ void ds4x_kernel(const float* __restrict__ in, float* __restrict__ out, int total) {
    int idx = blockIdx.x * blockDim.x + threadIdx.x;
    if (idx >= total) return;
    int x = idx & 63;
    int t = idx >> 6;
    int y = t & 63;
    int bc = t >> 6;
    const float* p = in + (size_t)bc * (HH * WW) + (4 * y + 1) * WW + 4 * x;
    float4 a = *(const float4*)p;
    float4 b = *(const float4*)(p + WW);
    out[idx] = 0.25f * (a.y + a.z + b.y + b.z);
}
template <int SCALE>
__global__ void corr_kernel(const float* __restrict__ f1, const float* __restrict__ f2,
                            const float* __restrict__ offs, float* __restrict__ out) {
    constexpr int S = (SCALE == 0) ? 256 : (SCALE == 1 ? 128 : 64);
    int x = blockIdx.x * 32 + (threadIdx.x & 31);
    int y = blockIdx.y * 8 + (threadIdx.x >> 5);
    int b = blockIdx.z;
    const float* offx = offs + ((size_t)b * 6 + 2 * SCALE) * (HH * WW);
    const float* offy = offx + HH * WW;
    float dx, dy;
    if constexpr (SCALE == 0) {
        dx = offx[y * WW + x];
        dy = offy[y * WW + x];
    } else if constexpr (SCALE == 1) {
        const float* px = offx + (2 * y) * WW + 2 * x;
        const float* py = offy + (2 * y) * WW + 2 * x;
        dx = 0.125f * (px[0] + px[1] + px[WW] + px[WW + 1]);
        dy = 0.125f * (py[0] + py[1] + py[WW] + py[WW + 1]);
    } else {
        const float* px = offx + (4 * y + 1) * WW + 4 * x + 1;
        const float* py = offy + (4 * y + 1) * WW + 4 * x + 1;
        dx = 0.0625f * (px[0] + px[1] + px[WW] + px[WW + 1]);
        dy = 0.0625f * (py[0] + py[1] + py[WW] + py[WW + 1]);
    }
    float sx = (float)x + dx;
    float sy = (float)y + dy;
    float x0f = floorf(sx), y0f = floorf(sy);
    float wx1 = sx - x0f, wy1 = sy - y0f;
    float wx0 = 1.0f - wx1, wy0 = 1.0f - wy1;
    int x0 = (int)x0f, y0 = (int)y0f;
    int x1 = x0 + 1, y1 = y0 + 1;
    bool vx0 = (x0 >= 0) & (x0 < S);
    bool vx1 = (x1 >= 0) & (x1 < S);
    bool vy0 = (y0 >= 0) & (y0 < S);
    bool vy1 = (y1 >= 0) & (y1 < S);
    float w00 = wy0 * wx0 * (float)(vy0 & vx0);
    float w01 = wy0 * wx1 * (float)(vy0 & vx1);
    float w10 = wy1 * wx0 * (float)(vy1 & vx0);
    float w11 = wy1 * wx1 * (float)(vy1 & vx1);
    int cx0 = min(max(x0, 0), S - 1), cx1 = min(max(x1, 0), S - 1);
    int cy0 = min(max(y0, 0), S - 1), cy1 = min(max(y1, 0), S - 1);
    int i00 = cy0 * S + cx0, i01 = cy0 * S + cx1;
    int i10 = cy1 * S + cx0, i11 = cy1 * S + cx1;
    const float* f1p = f1 + ((size_t)b * NC) * (S * S) + y * S + x;
    const float* f2p = f2 + ((size_t)b * NC) * (S * S);
    float acc = 0.0f;
#pragma unroll 4
    for (int c = 0; c < NC; ++c) {
        float sv = w00 * f2p[i00] + w01 * f2p[i01] + w10 * f2p[i10] + w11 * f2p[i11];
        acc = fmaf(f1p[0], sv, acc);
        f1p += S * S;
        f2p += S * S;
    }
    if constexpr (SCALE == 0) {
        out[((size_t)b * 3) * (HH * WW) + y * WW + x] = acc;
    } else {
        out[(size_t)b * (S * S) + y * S + x] = acc;
    }
}

extern "C" void kernel_launch(void* const* d_in, const int* in_sizes, int n_in,
                              void* d_out, int out_size, void* d_ws, size_t ws_size,
                              hipStream_t stream) {
    const float* feat1 = (const float*)d_in[0];
    const float* feat2 = (const float*)d_in[1];
    const float* offs  = (const float*)d_in[2];
    float* out = (float*)d_out;

    // ---- new path workspace (uints = bf16 pairs) ----
    const size_t n_s0 = (size_t)NB * HH * WW * 64;      // 16,777,216 uints
    const size_t n_d1 = (size_t)NB * 128 * 128 * 64;    //  4,194,304
    const size_t n_d2 = (size_t)NB * 64 * 64 * 64;      //  1,048,576
    const size_t n_c1 = (size_t)NB * 128 * 128;
    const size_t n_c2 = (size_t)NB * 64 * 64;
    const size_t need = (2 * (n_s0 + n_d1 + n_d2) + n_c1 + n_c2) * 4;

    if (ws_size >= need) {
        unsigned int* ws = (unsigned int*)d_ws;
        unsigned int* s0f1 = ws;
        unsigned int* s0f2 = s0f1 + n_s0;
        unsigned int* d1f1 = s0f2 + n_s0;
        unsigned int* d1f2 = d1f1 + n_d1;
        unsigned int* d2f1 = d1f2 + n_d1;
        unsigned int* d2f2 = d2f1 + n_d2;
        float* corr1 = (float*)(d2f2 + n_d2);
        float* corr2 = corr1 + n_c1;

        prep_kernel<<<dim3(16, 64, NB), 256, 0, stream>>>(feat1, s0f1, d1f1, d2f1);
        prep_kernel<<<dim3(16, 64, NB), 256, 0, stream>>>(feat2, s0f2, d1f2, d2f2);

        corr_hwc<0><<<NB * 65536 / 16, 256, 0, stream>>>(s0f1, s0f2, offs, out);
        corr_hwc<1><<<NB * 16384 / 16, 256, 0, stream>>>(d1f1, d1f2, offs, corr1);
        corr_hwc<2><<<NB * 4096 / 16, 256, 0, stream>>>(d2f1, d2f2, offs, corr2);

        up_kernel<1><<<(NB * HH * WW + 255) / 256, 256, 0, stream>>>(corr1, out);
        up_kernel<2><<<(NB * HH * WW + 255) / 256, 256, 0, stream>>>(corr2, out);
        return;
    }

    // ---- fallback: round-1 f32 CHW path ----
    const size_t n_ds1 = (size_t)NB * NC * 128 * 128;
    const size_t n_ds2 = (size_t)NB * NC * 64 * 64;
    const size_t need_fb = (2 * n_ds1 + 2 * n_ds2 + n_c1 + n_c2) * sizeof(float);
    if (ws_size < need_fb) return;
    float* ws = (float*)d_ws;
    float* ds1_f1 = ws;
    float* ds1_f2 = ds1_f1 + n_ds1;
    float* ds2_f1 = ds1_f2 + n_ds1;
    float* ds2_f2 = ds2_f1 + n_ds2;
    float* corr1  = ds2_f2 + n_ds2;
    float* corr2  = corr1 + n_c1;

    ds2x_kernel<<<(int)((n_ds1 + 255) / 256), 256, 0, stream>>>(feat1, ds1_f1, (int)n_ds1);
    ds2x_kernel<<<(int)((n_ds1 + 255) / 256), 256, 0, stream>>>(feat2, ds1_f2, (int)n_ds1);
    ds4x_kernel<<<(int)((n_ds2 + 255) / 256), 256, 0, stream>>>(feat1, ds2_f1, (int)n_ds2);
    ds4x_kernel<<<(int)((n_ds2 + 255) / 256), 256, 0, stream>>>(feat2, ds2_f2, (int)n_ds2);
    corr_kernel<0><<<dim3(8, 32, NB), 256, 0, stream>>>(feat1, feat2, offs, out);
    corr_kernel<1><<<dim3(4, 16, NB), 256, 0, stream>>>(ds1_f1, ds1_f2, offs, corr1);
    corr_kernel<2><<<dim3(2, 8, NB), 256, 0, stream>>>(ds2_f1, ds2_f2, offs, corr2);
    up_kernel<1><<<(NB * HH * WW + 255) / 256, 256, 0, stream>>>(corr1, out);
    up_kernel<2><<<(NB * HH * WW + 255) / 256, 256, 0, stream>>>(corr2, out);
}